// Round 4
// baseline (178.051 us; speedup 1.0000x reference)
//
#include <hip/hip_runtime.h>
#include <hip/hip_fp16.h>
#include <float.h>

#define NC 64     // clusters
#define FD 128    // feature dim
#define LSTR 136  // LDS row stride in halfs (pad 16B)

typedef _Float16 f16x8 __attribute__((ext_vector_type(8)));
typedef _Float16 f16x4 __attribute__((ext_vector_type(4)));
typedef float f32x4 __attribute__((ext_vector_type(4)));

// ---------------- prep: fp16 cast, |x|^2, histogram, Mt build, S zero, out zero ----
__global__ void prep_kernel(const float* __restrict__ feat,
                            const int* __restrict__ labels,
                            float* __restrict__ sq,
                            unsigned short* __restrict__ Xh,
                            unsigned short* __restrict__ Mt,
                            float* __restrict__ S,
                            float* __restrict__ out, int out_size,
                            int* __restrict__ counts, int N) {
  __shared__ int hist[NC];
  int t = threadIdx.x;
  if (t < NC) hist[t] = 0;
  __syncthreads();
  int row = blockIdx.x * 32 + (t >> 3);
  int o = t & 7;
  if (row < N) {
    const float* rp = feat + (size_t)row * FD;
    float s = 0.f;
#pragma unroll
    for (int j = 0; j < 4; ++j) {
      int c4 = o + 8 * j;
      float4 v = *(const float4*)(rp + c4 * 4);
      ushort4 h;
      h.x = __half_as_ushort(__float2half(v.x));   // RNE
      h.y = __half_as_ushort(__float2half(v.y));
      h.z = __half_as_ushort(__float2half(v.z));
      h.w = __half_as_ushort(__float2half(v.w));
      *(ushort4*)&Xh[(size_t)row * FD + c4 * 4] = h;
      s = fmaf(v.x, v.x, s); s = fmaf(v.y, v.y, s);
      s = fmaf(v.z, v.z, s); s = fmaf(v.w, v.w, s);
    }
    s += __shfl_xor(s, 1); s += __shfl_xor(s, 2); s += __shfl_xor(s, 4);
    if (o == 0) { sq[row] = s; atomicAdd(&hist[labels[row]], 1); }
  }
  // zero S rows for this block (32 rows x NC floats = 8 floats/thread)
  if ((blockIdx.x + 1) * 32 <= N) {
    float4 z = {0.f, 0.f, 0.f, 0.f};
    size_t base = (size_t)blockIdx.x * 32 * NC + t * 8;
    *(float4*)&S[base] = z;
    *(float4*)&S[base + 4] = z;
  }
  if (blockIdx.x == 0 && t < out_size) out[t] = 0.f;
  // build Mt[n][col] = (labels[col]==n) ? 1.0h : 0  (8-col chunks)
  {
    int chunksPerN = N >> 3;
    int total = NC * chunksPerN;
    for (int id = blockIdx.x * 256 + t; id < total; id += gridDim.x * 256) {
      int n = id / chunksPerN;
      int c0 = (id - n * chunksPerN) * 8;
      ushort4 lo, hi;
      lo.x = (labels[c0 + 0] == n) ? 0x3C00 : 0;
      lo.y = (labels[c0 + 1] == n) ? 0x3C00 : 0;
      lo.z = (labels[c0 + 2] == n) ? 0x3C00 : 0;
      lo.w = (labels[c0 + 3] == n) ? 0x3C00 : 0;
      hi.x = (labels[c0 + 4] == n) ? 0x3C00 : 0;
      hi.y = (labels[c0 + 5] == n) ? 0x3C00 : 0;
      hi.z = (labels[c0 + 6] == n) ? 0x3C00 : 0;
      hi.w = (labels[c0 + 7] == n) ? 0x3C00 : 0;
      *(ushort4*)&Mt[(size_t)n * N + c0] = lo;
      *(ushort4*)&Mt[(size_t)n * N + c0 + 4] = hi;
    }
  }
  __syncthreads();
  if (t < NC) atomicAdd(&counts[t], hist[t]);
}

// ---------------- main: fp16 MFMA Gram + IN-REGISTER MFMA segment-sum --------------
// V5: the dist-output fragment (transposed trick: lane(mm,quad) = row mm, cols
// quad*4+r) IS the A-operand layout of v_mfma_f32_16x16x16_f16 (lane: row=mm,
// k=quad*4..+3). So the epilogue's cvt_pkrtz pairs feed the segment-sum MFMA
// directly from registers: D's LDS round-trip and its two barriers are gone.
// 2 barriers/iter (stage WAR/RAW only); epi+S runs barrier-free so waves drift.
// Each wave segment-sums its own 32x64 sub-tile (K=16 per 16-col block); the 2
// wc-waves covering the same rows merge via the atomic flush (2x atomics, +17MB).
// 8 waves in 4x2 grid (32x64 tiles): AGPR = dacc 32 + sacc 32; VGPR ~75 ->
// ~110 total, V4-proven no-spill regime under (512,2).
// Tripwire: WRITE_SIZE must be ~33MB; >=45MB means spills came back.
__global__ __launch_bounds__(512, 2)
void mfma_tile_kernel(const unsigned short* __restrict__ Xh,
                      const float* __restrict__ sq,
                      const unsigned short* __restrict__ Mt,
                      float* __restrict__ S,
                      int N, int colsPerSplit) {
  __shared__ __align__(16) unsigned short Ah[128 * LSTR];  // 34816 B, A resident
  __shared__ __align__(16) unsigned short Bh[128 * LSTR];  // 34816 B, B stage only

  const int t = threadIdx.x;
  const int R = blockIdx.x * 128;
  const int cBeg = blockIdx.y * colsPerSplit;
  const int wave = t >> 6, lane = t & 63;
  const int mm = lane & 15, quad = lane >> 4;
  const int wr = wave >> 1, wc = wave & 1;   // 4x2 wave grid, 32x64 tiles
  const int numTiles = colsPerSplit / 128;

  // stage A full-K: 2048 x 16B chunks over 512 threads (4 per thread)
#pragma unroll
  for (int it = 0; it < 4; ++it) {
    int c = t + it * 512;
    int r = c >> 4, k0 = (c & 15) * 8;
    *(uint4*)&Ah[r * LSTR + k0] = *(const uint4*)&Xh[(size_t)(R + r) * FD + k0];
  }

  // per-lane row |x|^2: with transposed output, row = lane&15 within each ib tile
  float sqi_r[2];
#pragma unroll
  for (int ib = 0; ib < 2; ++ib)
    sqi_r[ib] = sq[R + wr * 32 + ib * 16 + mm];

  f32x4 sacc[2][4];                          // S accum: [ib row-tile][label-tile]
#pragma unroll
  for (int ib = 0; ib < 2; ++ib)
#pragma unroll
    for (int lt = 0; lt < 4; ++lt) sacc[ib][lt] = (f32x4)0.f;

  for (int ct = 0; ct < numTiles; ++ct) {
    const int C0 = cBeg + ct * 128;
    __syncthreads();                         // prev dist reads of Bh done (WAR)
#pragma unroll
    for (int it = 0; it < 4; ++it) {
      int c = t + it * 512;
      int r = c >> 4, k0 = (c & 15) * 8;
      *(uint4*)&Bh[r * LSTR + k0] = *(const uint4*)&Xh[(size_t)(C0 + r) * FD + k0];
    }
    // col |x|^2 as float4 (16B-aligned): cols = quad*4 + r within each jb tile
    float4 sjr[4];
#pragma unroll
    for (int jb = 0; jb < 4; ++jb)
      sjr[jb] = *(const float4*)&sq[C0 + wc * 64 + jb * 16 + quad * 4];
    __syncthreads();                         // Bh staged (RAW)

    // Dist pass: operands swapped -> transposed C/D fragments (row=mm, col=quad*4+r)
    f32x4 dacc[2][4];                        // [ib][jb]
#pragma unroll
    for (int ib = 0; ib < 2; ++ib)
#pragma unroll
      for (int jb = 0; jb < 4; ++jb) dacc[ib][jb] = (f32x4)0.f;

#pragma unroll
    for (int ks = 0; ks < 4; ++ks) {
      const int ko = ks * 32 + quad * 8;
      f16x8 af[2], bf[4];
#pragma unroll
      for (int ib = 0; ib < 2; ++ib)
        af[ib] = *(const f16x8*)&Ah[(wr * 32 + ib * 16 + mm) * LSTR + ko];
#pragma unroll
      for (int jb = 0; jb < 4; ++jb)
        bf[jb] = *(const f16x8*)&Bh[(wc * 64 + jb * 16 + mm) * LSTR + ko];
#pragma unroll
      for (int ib = 0; ib < 2; ++ib)
#pragma unroll
        for (int jb = 0; jb < 4; ++jb)
          dacc[ib][jb] = __builtin_amdgcn_mfma_f32_16x16x32_f16(bf[jb], af[ib], dacc[ib][jb], 0, 0, 0);
    }

    // epilogue + segment-sum, fully in registers, NO barriers:
    // d fragment (row=mm, cols quad*4+r of 16-col block jb) == A-frag of 16x16x16
    const bool hasDiag = (R == C0);
#pragma unroll
    for (int jb = 0; jb < 4; ++jb) {
      const int colBase = wc * 64 + jb * 16 + quad * 4;
      f16x4 mb[4];                           // Mt B-frags: lane(mm,quad) k=quad*4..+3
#pragma unroll
      for (int lt = 0; lt < 4; ++lt)
        mb[lt] = *(const f16x4*)&Mt[(size_t)(lt * 16 + mm) * N + C0 + colBase];
#pragma unroll
      for (int ib = 0; ib < 2; ++ib) {
        const int rowLocal = wr * 32 + ib * 16 + mm;
        const float si = sqi_r[ib];
        float d[4];
#pragma unroll
        for (int r = 0; r < 4; ++r) {
          float sj = (r == 0) ? sjr[jb].x : (r == 1) ? sjr[jb].y
                   : (r == 2) ? sjr[jb].z : sjr[jb].w;
          float d2 = fmaf(-2.f, dacc[ib][jb][r], si + sj);
          d[r] = __builtin_amdgcn_sqrtf(fmaxf(d2, 0.f));  // sqrt(0)=0: grad-safe
        }
        if (hasDiag) {                       // wave-uniform; 1 of numTiles iterations
#pragma unroll
          for (int r = 0; r < 4; ++r)
            if (rowLocal == colBase + r) d[r] = 0.f;
        }
        uint2 pk;
        pk.x = __builtin_bit_cast(unsigned, __builtin_amdgcn_cvt_pkrtz(d[0], d[1]));
        pk.y = __builtin_bit_cast(unsigned, __builtin_amdgcn_cvt_pkrtz(d[2], d[3]));
        f16x4 da = __builtin_bit_cast(f16x4, pk);
#pragma unroll
        for (int lt = 0; lt < 4; ++lt)
          sacc[ib][lt] = __builtin_amdgcn_mfma_f32_16x16x16f16(da, mb[lt], sacc[ib][lt], 0, 0, 0);
      }
    }
  }

  // flush: wc-wave pairs and colSplit blocks merge via atomics
#pragma unroll
  for (int ib = 0; ib < 2; ++ib)
#pragma unroll
    for (int lt = 0; lt < 4; ++lt)
#pragma unroll
      for (int r = 0; r < 4; ++r) {
        int rowD = wr * 32 + ib * 16 + quad * 4 + r;
        atomicAdd(&S[(size_t)(R + rowD) * NC + lt * 16 + mm], sacc[ib][lt][r]);
      }
}

// ---------------- score: a, b, silhouette, mean (vectorized) ----------------
__global__ void score_kernel(const float* __restrict__ S,
                             const int* __restrict__ labels,
                             const int* __restrict__ counts,
                             float* __restrict__ out, int N) {
  __shared__ float cnt_s[NC];
  __shared__ float inv_s[NC];
  __shared__ float red[128];
  int t = threadIdx.x;
  if (t < NC) {
    float c = (float)counts[t];
    cnt_s[t] = c;
    inv_s[t] = 1.f / fmaxf(c, 1.f);
  }
  __syncthreads();
  int i = blockIdx.x * 128 + t;
  float score = 0.f;
  if (i < N) {
    int li = labels[i];
    float own = cnt_s[li];
    const float4* Sv = (const float4*)(S + (size_t)i * NC);
    float a = S[(size_t)i * NC + li] / fmaxf(own - 1.f, 1.f);
    float b = FLT_MAX;
#pragma unroll
    for (int c4 = 0; c4 < NC / 4; ++c4) {
      float4 v = Sv[c4];
      int c = c4 * 4;
      float m0 = v.x * inv_s[c + 0];
      float m1 = v.y * inv_s[c + 1];
      float m2 = v.z * inv_s[c + 2];
      float m3 = v.w * inv_s[c + 3];
      b = fminf(b, (c + 0 == li || cnt_s[c + 0] == 0.f) ? FLT_MAX : m0);
      b = fminf(b, (c + 1 == li || cnt_s[c + 1] == 0.f) ? FLT_MAX : m1);
      b = fminf(b, (c + 2 == li || cnt_s[c + 2] == 0.f) ? FLT_MAX : m2);
      b = fminf(b, (c + 3 == li || cnt_s[c + 3] == 0.f) ? FLT_MAX : m3);
    }
    float mx = fmaxf(a, b);
    score = (own > 1.f) ? (b - a) / mx : 0.f;
  }
  red[t] = score;
  __syncthreads();
  for (int sft = 64; sft > 0; sft >>= 1) {
    if (t < sft) red[t] += red[t + sft];
    __syncthreads();
  }
  if (t == 0) atomicAdd(out, red[0] / (float)N);
}

extern "C" void kernel_launch(void* const* d_in, const int* in_sizes, int n_in,
                              void* d_out, int out_size, void* d_ws, size_t ws_size,
                              hipStream_t stream) {
  const float* feat = (const float*)d_in[0];
  const int* labels = (const int*)d_in[1];
  const int N = in_sizes[1];            // 8192; D=128, C=64 fixed by the reference
  float* out = (float*)d_out;
  char* ws = (char*)d_ws;

  // ws: counts(256B) | sq(N*4) | Xh(N*128*2) | Mt(64*N*2) | S(N*64*4)  ~5.03 MB @8192
  int*   counts = (int*)ws;
  float* sq     = (float*)(ws + 256);
  size_t o = 256 + (size_t)N * 4;
  o = (o + 255) & ~(size_t)255;
  unsigned short* Xh = (unsigned short*)(ws + o);                       // N*FD*2
  unsigned short* Mt = (unsigned short*)(ws + o + (size_t)N * FD * 2);  // NC*N*2
  float* S = (float*)(ws + o + (size_t)N * FD * 2 + (size_t)NC * N * 2);

  (void)hipMemsetAsync(counts, 0, 256, stream);

  prep_kernel<<<(N + 31) / 32, 256, 0, stream>>>(feat, labels, sq, Xh, Mt, S,
                                                 out, out_size, counts, N);

  const int colSplit = 8;               // 64 x 8 = 512 blocks = 2/CU (8 waves each)
  dim3 grid(N / 128, colSplit);
  mfma_tile_kernel<<<grid, 512, 0, stream>>>(Xh, sq, Mt, S, N, N / colSplit);

  score_kernel<<<(N + 127) / 128, 128, 0, stream>>>(S, labels, counts, out, N);
}

// Round 5
// 142.887 us; speedup vs baseline: 1.2461x; 1.2461x over previous
//
#include <hip/hip_runtime.h>
#include <hip/hip_fp16.h>
#include <float.h>

#define NC 64     // clusters
#define FD 128    // feature dim
#define LSTR 136  // LDS row stride in halfs (pad 16B)

typedef _Float16 f16x8 __attribute__((ext_vector_type(8)));
typedef _Float16 f16x4 __attribute__((ext_vector_type(4)));
typedef float f32x4 __attribute__((ext_vector_type(4)));

// ---------------- prep: fp16 cast, |x|^2, histogram, Mt build, S zero, out zero ----
__global__ void prep_kernel(const float* __restrict__ feat,
                            const int* __restrict__ labels,
                            float* __restrict__ sq,
                            unsigned short* __restrict__ Xh,
                            unsigned short* __restrict__ Mt,
                            float* __restrict__ S,
                            float* __restrict__ out, int out_size,
                            int* __restrict__ counts, int N) {
  __shared__ int hist[NC];
  int t = threadIdx.x;
  if (t < NC) hist[t] = 0;
  __syncthreads();
  int row = blockIdx.x * 32 + (t >> 3);
  int o = t & 7;
  if (row < N) {
    const float* rp = feat + (size_t)row * FD;
    float s = 0.f;
#pragma unroll
    for (int j = 0; j < 4; ++j) {
      int c4 = o + 8 * j;
      float4 v = *(const float4*)(rp + c4 * 4);
      ushort4 h;
      h.x = __half_as_ushort(__float2half(v.x));   // RNE
      h.y = __half_as_ushort(__float2half(v.y));
      h.z = __half_as_ushort(__float2half(v.z));
      h.w = __half_as_ushort(__float2half(v.w));
      *(ushort4*)&Xh[(size_t)row * FD + c4 * 4] = h;
      s = fmaf(v.x, v.x, s); s = fmaf(v.y, v.y, s);
      s = fmaf(v.z, v.z, s); s = fmaf(v.w, v.w, s);
    }
    s += __shfl_xor(s, 1); s += __shfl_xor(s, 2); s += __shfl_xor(s, 4);
    if (o == 0) { sq[row] = s; atomicAdd(&hist[labels[row]], 1); }
  }
  // zero S rows for this block (32 rows x NC floats = 8 floats/thread)
  if ((blockIdx.x + 1) * 32 <= N) {
    float4 z = {0.f, 0.f, 0.f, 0.f};
    size_t base = (size_t)blockIdx.x * 32 * NC + t * 8;
    *(float4*)&S[base] = z;
    *(float4*)&S[base + 4] = z;
  }
  if (blockIdx.x == 0 && t < out_size) out[t] = 0.f;
  // build Mt[n][col] = (labels[col]==n) ? 1.0h : 0  (8-col chunks)
  {
    int chunksPerN = N >> 3;
    int total = NC * chunksPerN;
    for (int id = blockIdx.x * 256 + t; id < total; id += gridDim.x * 256) {
      int n = id / chunksPerN;
      int c0 = (id - n * chunksPerN) * 8;
      ushort4 lo, hi;
      lo.x = (labels[c0 + 0] == n) ? 0x3C00 : 0;
      lo.y = (labels[c0 + 1] == n) ? 0x3C00 : 0;
      lo.z = (labels[c0 + 2] == n) ? 0x3C00 : 0;
      lo.w = (labels[c0 + 3] == n) ? 0x3C00 : 0;
      hi.x = (labels[c0 + 4] == n) ? 0x3C00 : 0;
      hi.y = (labels[c0 + 5] == n) ? 0x3C00 : 0;
      hi.z = (labels[c0 + 6] == n) ? 0x3C00 : 0;
      hi.w = (labels[c0 + 7] == n) ? 0x3C00 : 0;
      *(ushort4*)&Mt[(size_t)n * N + c0] = lo;
      *(ushort4*)&Mt[(size_t)n * N + c0 + 4] = hi;
    }
  }
  __syncthreads();
  if (t < NC) atomicAdd(&counts[t], hist[t]);
}

// ---------------- main: fp16 MFMA Gram + IN-REGISTER MFMA segment-sum --------------
// V6 = V1's winning shape (256 thr, 4 waves in 2x2 grid, 64x64 wave tiles,
// 2 blocks/CU) + V5's verified in-register segment-sum. Cross-round evidence:
// V1(4w,2blk,4bar)=60us < V4(8w,2blk,5bar)=91 < V5(8w,1blk,2bar)=111 -> what
// matters is 4-wave barrier width + >=2 blocks/CU phase overlap. V6 keeps both
// and cuts V1's 4 barriers/iter to 2 by dropping the D LDS round-trip: the dist
// fragment (row=mm, cols quad*4+r) IS the 16x16x16 A-frag, so cvt_pkrtz feeds
// the segment-sum MFMA from registers (V5-verified, absmax=0). epi+S is
// barrier-free; the co-resident block's stage/dist hides under it.
// Regs: dacc 64 + sacc 64 acc + ~110 arch ~= 238 <= 256 cap at (256,2) (V1-proven).
// Tripwire: WRITE_SIZE ~33MB (2x wc-dup flush); >=45MB means spill came back.
__global__ __launch_bounds__(256, 2)
void mfma_tile_kernel(const unsigned short* __restrict__ Xh,
                      const float* __restrict__ sq,
                      const unsigned short* __restrict__ Mt,
                      float* __restrict__ S,
                      int N, int colsPerSplit) {
  __shared__ __align__(16) unsigned short Ah[128 * LSTR];  // 34816 B, A resident
  __shared__ __align__(16) unsigned short Bh[128 * LSTR];  // 34816 B, B stage only

  const int t = threadIdx.x;
  const int R = blockIdx.x * 128;
  const int cBeg = blockIdx.y * colsPerSplit;
  const int wave = t >> 6, lane = t & 63;
  const int mm = lane & 15, quad = lane >> 4;
  const int wr = wave >> 1, wc = wave & 1;   // 2x2 wave grid, 64x64 tiles
  const int numTiles = colsPerSplit / 128;

  // stage A full-K: 2048 x 16B chunks over 256 threads (8 per thread)
#pragma unroll
  for (int it = 0; it < 8; ++it) {
    int c = t + it * 256;
    int r = c >> 4, k0 = (c & 15) * 8;
    *(uint4*)&Ah[r * LSTR + k0] = *(const uint4*)&Xh[(size_t)(R + r) * FD + k0];
  }

  // per-lane row |x|^2: with transposed output, row = lane&15 within each ib tile
  float sqi_r[4];
#pragma unroll
  for (int ib = 0; ib < 4; ++ib)
    sqi_r[ib] = sq[R + wr * 64 + ib * 16 + mm];

  f32x4 sacc[4][4];                          // S accum: [ib row-tile][label-tile]
#pragma unroll
  for (int ib = 0; ib < 4; ++ib)
#pragma unroll
    for (int lt = 0; lt < 4; ++lt) sacc[ib][lt] = (f32x4)0.f;

  for (int ct = 0; ct < numTiles; ++ct) {
    const int C0 = cBeg + ct * 128;
    __syncthreads();                         // WAR: prev dist reads of Bh done
#pragma unroll
    for (int it = 0; it < 8; ++it) {
      int c = t + it * 256;
      int r = c >> 4, k0 = (c & 15) * 8;
      *(uint4*)&Bh[r * LSTR + k0] = *(const uint4*)&Xh[(size_t)(C0 + r) * FD + k0];
    }
    // col |x|^2 as float4 (16B-aligned): cols = quad*4 + r within each jb tile
    float4 sjr[4];
#pragma unroll
    for (int jb = 0; jb < 4; ++jb)
      sjr[jb] = *(const float4*)&sq[C0 + wc * 64 + jb * 16 + quad * 4];
    __syncthreads();                         // RAW: Bh staged

    // Dist pass: operands swapped -> transposed C/D fragments (row=mm, col=quad*4+r)
    f32x4 dacc[4][4];                        // [ib][jb]
#pragma unroll
    for (int ib = 0; ib < 4; ++ib)
#pragma unroll
      for (int jb = 0; jb < 4; ++jb) dacc[ib][jb] = (f32x4)0.f;

#pragma unroll
    for (int ks = 0; ks < 4; ++ks) {
      const int ko = ks * 32 + quad * 8;
      f16x8 af[4], bf[4];
#pragma unroll
      for (int ib = 0; ib < 4; ++ib)
        af[ib] = *(const f16x8*)&Ah[(wr * 64 + ib * 16 + mm) * LSTR + ko];
#pragma unroll
      for (int jb = 0; jb < 4; ++jb)
        bf[jb] = *(const f16x8*)&Bh[(wc * 64 + jb * 16 + mm) * LSTR + ko];
#pragma unroll
      for (int ib = 0; ib < 4; ++ib)
#pragma unroll
        for (int jb = 0; jb < 4; ++jb)
          dacc[ib][jb] = __builtin_amdgcn_mfma_f32_16x16x32_f16(bf[jb], af[ib], dacc[ib][jb], 0, 0, 0);
    }

    // epilogue + segment-sum, fully in registers, NO barriers:
    // d fragment (row=mm, cols quad*4+r of 16-col block jb) == A-frag of 16x16x16
    const bool hasDiag = (R == C0);
#pragma unroll
    for (int jb = 0; jb < 4; ++jb) {
      const int colBase = wc * 64 + jb * 16 + quad * 4;
      f16x4 mb[4];                           // Mt B-frags: lane(mm,quad) k=quad*4..+3
#pragma unroll
      for (int lt = 0; lt < 4; ++lt)
        mb[lt] = *(const f16x4*)&Mt[(size_t)(lt * 16 + mm) * N + C0 + colBase];
#pragma unroll
      for (int ib = 0; ib < 4; ++ib) {
        const int rowLocal = wr * 64 + ib * 16 + mm;
        const float si = sqi_r[ib];
        float d[4];
#pragma unroll
        for (int r = 0; r < 4; ++r) {
          float sj = (r == 0) ? sjr[jb].x : (r == 1) ? sjr[jb].y
                   : (r == 2) ? sjr[jb].z : sjr[jb].w;
          float d2 = fmaf(-2.f, dacc[ib][jb][r], si + sj);
          d[r] = __builtin_amdgcn_sqrtf(fmaxf(d2, 0.f));  // sqrt(0)=0: grad-safe
        }
        if (hasDiag) {                       // wave-uniform; 1 of numTiles iterations
#pragma unroll
          for (int r = 0; r < 4; ++r)
            if (rowLocal == colBase + r) d[r] = 0.f;
        }
        uint2 pk;
        pk.x = __builtin_bit_cast(unsigned, __builtin_amdgcn_cvt_pkrtz(d[0], d[1]));
        pk.y = __builtin_bit_cast(unsigned, __builtin_amdgcn_cvt_pkrtz(d[2], d[3]));
        f16x4 da = __builtin_bit_cast(f16x4, pk);
#pragma unroll
        for (int lt = 0; lt < 4; ++lt)
          sacc[ib][lt] = __builtin_amdgcn_mfma_f32_16x16x16f16(da, mb[lt], sacc[ib][lt], 0, 0, 0);
      }
    }
  }

  // flush: wc-wave pairs and colSplit blocks merge via atomics
  // 16x16x16 C/D layout: col = mm (label), row = quad*4 + r within ib strip
#pragma unroll
  for (int ib = 0; ib < 4; ++ib)
#pragma unroll
    for (int lt = 0; lt < 4; ++lt)
#pragma unroll
      for (int r = 0; r < 4; ++r) {
        int rowD = wr * 64 + ib * 16 + quad * 4 + r;
        atomicAdd(&S[(size_t)(R + rowD) * NC + lt * 16 + mm], sacc[ib][lt][r]);
      }
}

// ---------------- score: a, b, silhouette, mean (vectorized) ----------------
__global__ void score_kernel(const float* __restrict__ S,
                             const int* __restrict__ labels,
                             const int* __restrict__ counts,
                             float* __restrict__ out, int N) {
  __shared__ float cnt_s[NC];
  __shared__ float inv_s[NC];
  __shared__ float red[128];
  int t = threadIdx.x;
  if (t < NC) {
    float c = (float)counts[t];
    cnt_s[t] = c;
    inv_s[t] = 1.f / fmaxf(c, 1.f);
  }
  __syncthreads();
  int i = blockIdx.x * 128 + t;
  float score = 0.f;
  if (i < N) {
    int li = labels[i];
    float own = cnt_s[li];
    const float4* Sv = (const float4*)(S + (size_t)i * NC);
    float a = S[(size_t)i * NC + li] / fmaxf(own - 1.f, 1.f);
    float b = FLT_MAX;
#pragma unroll
    for (int c4 = 0; c4 < NC / 4; ++c4) {
      float4 v = Sv[c4];
      int c = c4 * 4;
      float m0 = v.x * inv_s[c + 0];
      float m1 = v.y * inv_s[c + 1];
      float m2 = v.z * inv_s[c + 2];
      float m3 = v.w * inv_s[c + 3];
      b = fminf(b, (c + 0 == li || cnt_s[c + 0] == 0.f) ? FLT_MAX : m0);
      b = fminf(b, (c + 1 == li || cnt_s[c + 1] == 0.f) ? FLT_MAX : m1);
      b = fminf(b, (c + 2 == li || cnt_s[c + 2] == 0.f) ? FLT_MAX : m2);
      b = fminf(b, (c + 3 == li || cnt_s[c + 3] == 0.f) ? FLT_MAX : m3);
    }
    float mx = fmaxf(a, b);
    score = (own > 1.f) ? (b - a) / mx : 0.f;
  }
  red[t] = score;
  __syncthreads();
  for (int sft = 64; sft > 0; sft >>= 1) {
    if (t < sft) red[t] += red[t + sft];
    __syncthreads();
  }
  if (t == 0) atomicAdd(out, red[0] / (float)N);
}

extern "C" void kernel_launch(void* const* d_in, const int* in_sizes, int n_in,
                              void* d_out, int out_size, void* d_ws, size_t ws_size,
                              hipStream_t stream) {
  const float* feat = (const float*)d_in[0];
  const int* labels = (const int*)d_in[1];
  const int N = in_sizes[1];            // 8192; D=128, C=64 fixed by the reference
  float* out = (float*)d_out;
  char* ws = (char*)d_ws;

  // ws: counts(256B) | sq(N*4) | Xh(N*128*2) | Mt(64*N*2) | S(N*64*4)  ~5.03 MB @8192
  int*   counts = (int*)ws;
  float* sq     = (float*)(ws + 256);
  size_t o = 256 + (size_t)N * 4;
  o = (o + 255) & ~(size_t)255;
  unsigned short* Xh = (unsigned short*)(ws + o);                       // N*FD*2
  unsigned short* Mt = (unsigned short*)(ws + o + (size_t)N * FD * 2);  // NC*N*2
  float* S = (float*)(ws + o + (size_t)N * FD * 2 + (size_t)NC * N * 2);

  (void)hipMemsetAsync(counts, 0, 256, stream);

  prep_kernel<<<(N + 31) / 32, 256, 0, stream>>>(feat, labels, sq, Xh, Mt, S,
                                                 out, out_size, counts, N);

  const int colSplit = 8;               // 64 x 8 = 512 blocks = 2/CU (4 waves each)
  dim3 grid(N / 128, colSplit);
  mfma_tile_kernel<<<grid, 256, 0, stream>>>(Xh, sq, Mt, S, N, N / colSplit);

  score_kernel<<<(N + 127) / 128, 128, 0, stream>>>(S, labels, counts, out, N);
}